// Round 12
// baseline (350.774 us; speedup 1.0000x reference)
//
#include <hip/hip_runtime.h>

#define NI 2048
#define NB 64
#define NC 32
#define DC 16
#define DI 8

static constexpr float SQ_EPS = 1e-7f;

// SSA vector type: never an alloca, never scratch (R8 lesson).
typedef float f8 __attribute__((ext_vector_type(8)));

// Routing pass, W streamed from LDS in 2-capsule sub-tiles, b-quad/wave.
// R11 post-mortem: xbuf was statically 8 KB (sized for the ncap=16
// fallback) -> LDS 41984 B -> only 3 blocks/CU (needed 4) + a 256-block
// tail at 1/4 occupancy = 59 us. Fix: NCAP is a template param, xbuf
// sized 16*2*NCAP float4 -> LDS 37888 B at NCAP=8 -> exactly 4 blocks/CU
// (151.5 KB of 160 KB), 16 waves/CU, no tail.
// Lane = (c = lane&31, dg = lane>>5); wave owns b-quad by*16 + wave*4.
// MODE 0: uniform coupling 1/32. MODE 1: logits = dot(u, veff),
// veff transposed [b][dg][c][8].
template <int MODE, int NCAP>
__global__
__attribute__((amdgpu_flat_work_group_size(256, 256), amdgpu_waves_per_eu(4, 4)))
void route_pass(
    const float* __restrict__ x, const float* __restrict__ W,
    const float* __restrict__ veff, float* __restrict__ partial)
{
    // W sub-tile (2 capsules): float4 [(il*16 + k10)*2 + kdg][c 32 +1 pad]
    // stride 33 -> in-loop c-contiguous reads, 2-way max bank aliasing.
    __shared__ float4 wbuf[2112];              // 33 KB
    __shared__ float4 xbuf[16 * 2 * NCAP];     // [brel 16][cap*2+half]

    constexpr int LG = (NCAP == 8) ? 4 : 5;    // log2(NCAP*2)
    const int tid  = threadIdx.x;
    const int wave = tid >> 6;
    const int lane = tid & 63;
    const int c    = lane & 31;
    const int dg   = lane >> 5;
    const int brel0 = wave * 4;
    const int b0g  = blockIdx.y * 16;
    const int b0   = b0g + brel0;
    const int i0   = blockIdx.x * NCAP;

    f8 s0 = {}, s1 = {}, s2 = {}, s3 = {};
    f8 va = {}, vb = {}, vc = {}, vd = {};
    if (MODE == 1) {
        va = *reinterpret_cast<const f8*>(veff + (((size_t)(b0+0)*2 + dg)*32 + c)*8);
        vb = *reinterpret_cast<const f8*>(veff + (((size_t)(b0+1)*2 + dg)*32 + c)*8);
        vc = *reinterpret_cast<const f8*>(veff + (((size_t)(b0+2)*2 + dg)*32 + c)*8);
        vd = *reinterpret_cast<const f8*>(veff + (((size_t)(b0+3)*2 + dg)*32 + c)*8);
    }

    const float4* Wf4 = reinterpret_cast<const float4*>(W);
    const float4* Xf4 = reinterpret_cast<const float4*>(x);

    // ---- stage x tile once: 16 b x NCAP i x 8 f
    for (int idx = tid; idx < (16 << LG); idx += 256) {
        const int brel = idx >> LG;
        const int rem  = idx & ((1 << LG) - 1);       // cap*2 + half
        xbuf[(brel << LG) + rem] =
            Xf4[((size_t)(b0g + brel) * NI + i0 + (rem >> 1)) * 2 + (rem & 1)];
    }

    const int kk  = tid & 31;          // f4 index within a (c,i) W row
    const int p0  = tid >> 5;          // 0..7
    const int k10 = kk & 15, kdg = kk >> 4;

    for (int st = 0; st < (NCAP >> 1); ++st) {
        const int i0s = i0 + st * 2;
        __syncthreads();               // previous sub-tile's readers done
        // ---- stage 2-capsule W sub-tile (coalesced 512 B runs)
#pragma unroll
        for (int r = 0; r < 8; ++r) {
            const int p  = r * 8 + p0;     // 0..63 = (cc 32, il 2)
            const int cc = p >> 1;
            const int il = p & 1;
            wbuf[((il * 16 + k10) * 2 + kdg) * 33 + cc] =
                Wf4[((size_t)cc * NI + i0s + il) * 32 + kk];
        }
        __syncthreads();

#pragma unroll
        for (int il = 0; il < 2; ++il) {
            const int cap = st * 2 + il;
            const float4 xa0 = xbuf[((brel0+0) << LG) + cap*2], xa1 = xbuf[((brel0+0) << LG) + cap*2 + 1];
            const float4 xb0 = xbuf[((brel0+1) << LG) + cap*2], xb1 = xbuf[((brel0+1) << LG) + cap*2 + 1];
            const float4 xc0 = xbuf[((brel0+2) << LG) + cap*2], xc1 = xbuf[((brel0+2) << LG) + cap*2 + 1];
            const float4 xd0 = xbuf[((brel0+3) << LG) + cap*2], xd1 = xbuf[((brel0+3) << LG) + cap*2 + 1];

            f8 u0 = {}, u1 = {}, u2 = {}, u3 = {};
#pragma unroll
            for (int dd = 0; dd < 8; ++dd) {
                const float4 wl = wbuf[((il*16 + dd*2    )*2 + dg)*33 + c];
                const float4 wh = wbuf[((il*16 + dd*2 + 1)*2 + dg)*33 + c];
                u0[dd] = wl.x*xa0.x + wl.y*xa0.y + wl.z*xa0.z + wl.w*xa0.w
                       + wh.x*xa1.x + wh.y*xa1.y + wh.z*xa1.z + wh.w*xa1.w;
                u1[dd] = wl.x*xb0.x + wl.y*xb0.y + wl.z*xb0.z + wl.w*xb0.w
                       + wh.x*xb1.x + wh.y*xb1.y + wh.z*xb1.z + wh.w*xb1.w;
                u2[dd] = wl.x*xc0.x + wl.y*xc0.y + wl.z*xc0.z + wl.w*xc0.w
                       + wh.x*xc1.x + wh.y*xc1.y + wh.z*xc1.z + wh.w*xc1.w;
                u3[dd] = wl.x*xd0.x + wl.y*xd0.y + wl.z*xd0.z + wl.w*xd0.w
                       + wh.x*xd1.x + wh.y*xd1.y + wh.z*xd1.z + wh.w*xd1.w;
            }

            if (MODE == 0) {
                const float cu = 1.0f / 32.0f;
                s0 += u0 * cu; s1 += u1 * cu; s2 += u2 * cu; s3 += u3 * cu;
            } else {
                // Pair-softmax: lower 32-half reduces even b, upper odd b;
                // one xor-32 merge in, one xor-32 coef-swap out.
#pragma unroll
                for (int pr = 0; pr < 2; ++pr) {
                    const f8& ue = pr ? u2 : u0;
                    const f8& uo = pr ? u3 : u1;
                    const f8& ve = pr ? vc : va;
                    const f8& vo = pr ? vd : vb;
                    float pe = 0.0f, po = 0.0f;
#pragma unroll
                    for (int k = 0; k < 8; ++k) {
                        pe += ue[k] * ve[k];
                        po += uo[k] * vo[k];
                    }
                    const float send = (dg == 0) ? po : pe;
                    const float recv = __shfl_xor(send, 32);
                    float a = ((dg == 0) ? pe : po) + recv;
                    float m = a;
#pragma unroll
                    for (int off = 16; off >= 1; off >>= 1)
                        m = fmaxf(m, __shfl_xor(m, off));
                    const float e = __expf(a - m);
                    float t = e;
#pragma unroll
                    for (int off = 16; off >= 1; off >>= 1)
                        t += __shfl_xor(t, off);
                    const float mine  = e / t;
                    const float other = __shfl_xor(mine, 32);
                    const float ce = (dg == 0) ? mine : other;
                    const float co = (dg == 0) ? other : mine;
                    if (pr == 0) { s0 += u0 * ce; s1 += u1 * co; }
                    else         { s2 += u2 * ce; s3 += u3 * co; }
                }
            }
        }
    }

    // ---- flush the wave's four s-partials (plain coalesced 32 B stores)
    // partial floats: [pblk][brel 16][dg 2][c 32][8]
    {
        const int pblk = blockIdx.y * gridDim.x + blockIdx.x;
        float* gp = partial +
            (((size_t)pblk * 16 + brel0) * 128 + dg * 64 + c * 2) * 4;
        *reinterpret_cast<f8*>(gp)        = s0;
        *reinterpret_cast<f8*>(gp +  512) = s1;
        *reinterpret_cast<f8*>(gp + 1024) = s2;
        *reinterpret_cast<f8*>(gp + 1536) = s3;
    }
}

// Fused partial reduction + squash. Squash's norm is per-(b,c), so split
// c across blocks too: 256 blocks = (b 64) x (c-octet 4), 256 threads =
// (part 8) x (ci 8 x dq 4). Each thread sums nib/8 slabs; LDS tree; the
// first 32 threads squash + write.
// phase 1: veff  = NI * squash(s)   (transposed [b][dg][c][8])
// phase 2: veff += NI * squash(s)
// phase 3: out   = squash(s)        (canonical [b][c][d])
__global__ __launch_bounds__(256) void reduce_squash(
    const float* __restrict__ partial, float* __restrict__ veff,
    float* __restrict__ out, int phase, int nib)
{
    __shared__ float4 red[256];
    const int b     = blockIdx.x >> 2;
    const int oct   = blockIdx.x & 3;
    const int tid   = threadIdx.x;
    const int part  = tid >> 5;
    const int inner = tid & 31;
    const int ci    = inner >> 2;
    const int c     = oct * 8 + ci;
    const int dq    = inner & 3;             // d = dq*4 + j
    const int chunk = nib >> 3;

    const float* base = partial
        + ((size_t)(b >> 4) * nib + part * chunk) * 8192
        + (b & 15) * 512 + (dq >> 1) * 256 + c * 8 + (dq & 1) * 4;
    float4 acc = make_float4(0.f, 0.f, 0.f, 0.f);
#pragma unroll 8
    for (int ib = 0; ib < chunk; ++ib) {
        const float4 p = *reinterpret_cast<const float4*>(base + (size_t)ib * 8192);
        acc.x += p.x; acc.y += p.y; acc.z += p.z; acc.w += p.w;
    }
    red[tid] = acc;
    __syncthreads();
    if (part == 0) {
#pragma unroll
        for (int p = 1; p < 8; ++p) {
            const float4 r = red[inner + p * 32];
            acc.x += r.x; acc.y += r.y; acc.z += r.z; acc.w += r.w;
        }

        float sq = acc.x*acc.x + acc.y*acc.y + acc.z*acc.z + acc.w*acc.w;
        sq += __shfl_xor(sq, 1);
        sq += __shfl_xor(sq, 2);
        const float scale = sq / ((1.0f + sq) * sqrtf(sq + SQ_EPS));

        if (phase == 3) {
            float4* op = reinterpret_cast<float4*>(
                out + ((size_t)b * NC + c) * DC + dq * 4);
            *op = make_float4(scale*acc.x, scale*acc.y, scale*acc.z, scale*acc.w);
        } else {
            const float ns = scale * (float)NI;
            float4* vp = reinterpret_cast<float4*>(
                veff + (((size_t)b * 2 + (dq >> 1)) * 32 + c) * 8 + (dq & 1) * 4);
            if (phase == 1) {
                *vp = make_float4(ns*acc.x, ns*acc.y, ns*acc.z, ns*acc.w);
            } else {
                float4 old = *vp;
                *vp = make_float4(old.x + ns*acc.x, old.y + ns*acc.y,
                                  old.z + ns*acc.z, old.w + ns*acc.w);
            }
        }
    }
}

extern "C" void kernel_launch(void* const* d_in, const int* in_sizes, int n_in,
                              void* d_out, int out_size, void* d_ws, size_t ws_size,
                              hipStream_t stream) {
    (void)in_sizes; (void)n_in; (void)out_size;
    const float* x = (const float*)d_in[0];
    const float* W = (const float*)d_in[1];

    float* partial = (float*)d_ws;
    float* veff    = (float*)d_out;     // scratch; phase-3 squash overwrites

    // 256 i-blocks needs 4*256 slabs * 32 KB = 33.6 MB of ws; fall back to
    // 128 i-blocks (16 capsules each, 16.8 MB) if the workspace is smaller.
    const bool big = (ws_size >= (size_t)4 * 256 * 8192 * 4);
    const int  nib = big ? 256 : 128;
    const dim3 grid(nib, 4);

    if (big) {
        route_pass<0, 8><<<grid, 256, 0, stream>>>(x, W, nullptr, partial);
        reduce_squash<<<256, 256, 0, stream>>>(partial, veff, nullptr, 1, nib);
        route_pass<1, 8><<<grid, 256, 0, stream>>>(x, W, veff, partial);
        reduce_squash<<<256, 256, 0, stream>>>(partial, veff, nullptr, 2, nib);
        route_pass<1, 8><<<grid, 256, 0, stream>>>(x, W, veff, partial);
        reduce_squash<<<256, 256, 0, stream>>>(partial, nullptr, (float*)d_out, 3, nib);
    } else {
        route_pass<0, 16><<<grid, 256, 0, stream>>>(x, W, nullptr, partial);
        reduce_squash<<<256, 256, 0, stream>>>(partial, veff, nullptr, 1, nib);
        route_pass<1, 16><<<grid, 256, 0, stream>>>(x, W, veff, partial);
        reduce_squash<<<256, 256, 0, stream>>>(partial, veff, nullptr, 2, nib);
        route_pass<1, 16><<<grid, 256, 0, stream>>>(x, W, veff, partial);
        reduce_squash<<<256, 256, 0, stream>>>(partial, nullptr, (float*)d_out, 3, nib);
    }
}